// Round 2
// baseline (101.919 us; speedup 1.0000x reference)
//
#include <hip/hip_runtime.h>

#define B_ 4
#define C_ 256
#define C2_ 128
#define N_ 4096
#define LOG2E_ 1.4426950408889634f
#define SHIFT2_ 43.28085122666891f   // 30 * log2(e); softmax in exp2 domain

typedef __bf16 bf16;
typedef __bf16 bf16x8 __attribute__((ext_vector_type(8)));
typedef __bf16 bf16x4 __attribute__((ext_vector_type(4)));
typedef __bf16 bf16x2 __attribute__((ext_vector_type(2)));
typedef float f32x4 __attribute__((ext_vector_type(4)));
typedef float f32x16 __attribute__((ext_vector_type(16)));
typedef unsigned int u32x4 __attribute__((ext_vector_type(4)));

__device__ __forceinline__ f32x4 mfma16(bf16x8 a, bf16x8 b, f32x4 c) {
  return __builtin_amdgcn_mfma_f32_16x16x32_bf16(a, b, c, 0, 0, 0);
}
__device__ __forceinline__ f32x16 mfma32(bf16x8 a, bf16x8 b, f32x16 c) {
  return __builtin_amdgcn_mfma_f32_32x32x16_bf16(a, b, c, 0, 0, 0);
}

__device__ __forceinline__ float fexp2(float x) {
#if __has_builtin(__builtin_amdgcn_exp2f)
  return __builtin_amdgcn_exp2f(x);
#else
  return exp2f(x);
#endif
}

// async global->LDS, 16B per lane (dest = wave-uniform base + lane*16)
typedef const __attribute__((address_space(1))) uint32_t* gas_ptr;
typedef __attribute__((address_space(3))) uint32_t* las_ptr;
__device__ __forceinline__ void gld_lds16(const bf16* g, bf16* l) {
  __builtin_amdgcn_global_load_lds((gas_ptr)g, (las_ptr)l, 16, 0, 0);
}

// pack two f32 -> one dword of 2 bf16
__device__ __forceinline__ uint32_t pk2(float a, float b) {
  bf16x2 v; v[0] = (bf16)a; v[1] = (bf16)b;
  return __builtin_bit_cast(uint32_t, v);
}
// v_permlane32_swap_b32: a[l>=32] <-> b[l<32]  (VALU cross-lane, no LDS pipe)
__device__ __forceinline__ void pl32swap(uint32_t& a, uint32_t& b) {
  asm volatile("v_permlane32_swap_b32 %0, %1" : "+v"(a), "+v"(b));
}

// exp2-domain softmax numerator + VALU row-sum partial + bf16 pack/transpose
__device__ __forceinline__ void exp_pack(const f32x16& s, float& lsum,
                                         bf16x8& pf0, bf16x8& pf1) {
  float p[16];
  #pragma unroll
  for (int r = 0; r < 16; ++r) p[r] = fexp2(s[r] - SHIFT2_);
  float a0 = (p[0] + p[1]) + (p[2] + p[3]);
  float a1 = (p[4] + p[5]) + (p[6] + p[7]);
  float a2 = (p[8] + p[9]) + (p[10] + p[11]);
  float a3 = (p[12] + p[13]) + (p[14] + p[15]);
  lsum += (a0 + a1) + (a2 + a3);
  uint32_t A[4], Bb[4];
  #pragma unroll
  for (int G = 0; G < 4; ++G) {
    A[G]  = pk2(p[4 * G + 0], p[4 * G + 1]);
    Bb[G] = pk2(p[4 * G + 2], p[4 * G + 3]);
  }
  pl32swap(A[0], A[1]);  pl32swap(Bb[0], Bb[1]);
  { u32x4 dv = {A[0], Bb[0], A[1], Bb[1]}; pf0 = __builtin_bit_cast(bf16x8, dv); }
  pl32swap(A[2], A[3]);  pl32swap(Bb[2], Bb[3]);
  { u32x4 dv = {A[2], Bb[2], A[3], Bb[3]}; pf1 = __builtin_bit_cast(bf16x8, dv); }
}

// 32x32x16 fragment layouts:
//  A/B: lane = idx%32 + 32*((k%16)/8), elem = k%8 (8 bf16 / 4 VGPRs)
//  C/D: col = lane&31, row = (reg&3) + 8*(reg>>2) + 4*(lane>>5)
// Operand storage (fragment-major, wave reads = linear 1KB):
//  theta/phi: [b][n/32][ks 8][64][8]   (theta pre-scaled by log2e)
//  g (V^T):   [b][n/32 chunk][dtile 4][ks2 2][64][8] (8KB per 32-row chunk)

// ---------------------------------------------------------------------------
// Kernel 1: fused 3-way 1x1-conv projections, fragment-major outputs.
// ---------------------------------------------------------------------------
__global__ __launch_bounds__(256) void proj_kernel(
    const float* __restrict__ x,
    const float* __restrict__ w0, const float* __restrict__ b0,
    const float* __restrict__ w1, const float* __restrict__ b1,
    const float* __restrict__ w2, const float* __restrict__ b2,
    bf16* __restrict__ o0, bf16* __restrict__ o1, bf16* __restrict__ o2)
{
  __shared__ bf16 Xs[64][C_];   // [n][c], 16B block cb swizzled: cb ^= (n&7)
  const int tid  = threadIdx.x;
  const int lane = tid & 63;
  const int w    = tid >> 6;
  const int n0   = blockIdx.x * 64;
  const int b    = blockIdx.y;
  const int l15  = lane & 15;
  const int lg   = lane >> 4;
  const float* xb = x + (size_t)b * C_ * N_;

  // stage X^T: thread owns row n=lane, wave w covers c in [64w, 64w+64)
  {
    const int nl = lane;
    #pragma unroll
    for (int g = 0; g < 8; ++g) {
      int c0 = w * 64 + g * 8;
      bf16x8 h;
      #pragma unroll
      for (int i = 0; i < 8; ++i)
        h[i] = (bf16)xb[(size_t)(c0 + i) * N_ + n0 + nl];
      int cbs = (c0 >> 3) ^ (nl & 7);
      *(bf16x8*)&Xs[nl][cbs * 8] = h;
    }
  }
  __syncthreads();

  const f32x4 fzero = {0.f, 0.f, 0.f, 0.f};
  f32x4 acc[3][2][4];
  #pragma unroll
  for (int p = 0; p < 3; ++p)
    #pragma unroll
    for (int ot = 0; ot < 2; ++ot)
      #pragma unroll
      for (int nt = 0; nt < 4; ++nt) acc[p][ot][nt] = fzero;

  const float* Wp[3] = {w0, w1, w2};
  const int arow = w * 32 + l15;
  const int kbase = lg * 8;

  for (int kc = 0; kc < 8; ++kc) {
    bf16x8 bfr[4];
    #pragma unroll
    for (int nt = 0; nt < 4; ++nt) {
      int n = nt * 16 + l15;
      int cbs = (kc * 4 + lg) ^ (n & 7);
      bfr[nt] = *(const bf16x8*)&Xs[n][cbs * 8];
    }
    #pragma unroll
    for (int p = 0; p < 3; ++p) {
      #pragma unroll
      for (int ot = 0; ot < 2; ++ot) {
        const float* wr = Wp[p] + (size_t)(arow + ot * 16) * C_ + kc * 32 + kbase;
        f32x4 lo = *(const f32x4*)wr;
        f32x4 hi = *(const f32x4*)(wr + 4);
        bf16x8 af;
        if (p == 0) {
          #pragma unroll
          for (int i = 0; i < 4; ++i) {
            af[i]     = (bf16)(lo[i] * LOG2E_);
            af[4 + i] = (bf16)(hi[i] * LOG2E_);
          }
        } else {
          #pragma unroll
          for (int i = 0; i < 4; ++i) { af[i] = (bf16)lo[i]; af[4 + i] = (bf16)hi[i]; }
        }
        #pragma unroll
        for (int nt = 0; nt < 4; ++nt)
          acc[p][ot][nt] = mfma16(af, bfr[nt], acc[p][ot][nt]);
      }
    }
  }

  // ---- theta (p=0, log2e-scaled), phi (p=1): [b][n/32][ks 8][64][8]
  const float* Bp[3] = {b0, b1, b2};
  bf16* Op2[2] = {o0, o1};
  #pragma unroll
  for (int p = 0; p < 2; ++p) {
    bf16* dst = Op2[p] + (size_t)b * 128 * 8 * 512;
    #pragma unroll
    for (int ot = 0; ot < 2; ++ot) {
      int ks = w * 2 + ot;            // c>>4 (c = w*32+ot*16+lg*4+j)
      float bv[4];
      #pragma unroll
      for (int j = 0; j < 4; ++j) {
        float t = Bp[p][w * 32 + ot * 16 + lg * 4 + j];
        bv[j] = (p == 0) ? t * LOG2E_ : t;
      }
      #pragma unroll
      for (int nt = 0; nt < 4; ++nt) {
        int qtile = (n0 >> 5) + (nt >> 1);
        int lanep = ((nt & 1) * 16 + l15) + 32 * (lg >> 1);
        int elemb = (lg & 1) * 4;
        bf16x4 ov;
        #pragma unroll
        for (int j = 0; j < 4; ++j) ov[j] = (bf16)(acc[p][ot][nt][j] + bv[j]);
        *(bf16x4*)(dst + ((size_t)(qtile * 8 + ks) * 64 + lanep) * 8 + elemb) = ov;
      }
    }
  }
  // ---- g (p=2): [b][n/32 chunk][dtile 4][ks2 2][64][8]  (8KB per chunk)
  {
    bf16* dst = o2 + (size_t)b * 128 * 4096;
    const int t32b = n0 >> 5;
    #pragma unroll
    for (int ot = 0; ot < 2; ++ot) {
      #pragma unroll
      for (int j = 0; j < 4; ++j) {
        float bv = b2[w * 32 + ot * 16 + lg * 4 + j];
        int d31 = ot * 16 + lg * 4 + j;        // d&31 (dtile = w)
        #pragma unroll
        for (int nt = 0; nt < 4; ++nt) {
          int t32 = t32b + (nt >> 1);          // 32-row chunk index
          int ks2 = nt & 1;                    // 16-row k-slice within chunk
          int lanep = d31 + 32 * (l15 >> 3);
          dst[((size_t)((t32 * 4 + w) * 2 + ks2) * 64 + lanep) * 8 + (l15 & 7)] =
              (bf16)(acc[2][ot][nt][j] + bv);
        }
      }
    }
  }
}

// ---------------------------------------------------------------------------
// Kernel 2: flash attention. 256 thr (4 waves), wave = 64 q-rows (2 subtiles),
// 64-row KV tiles dbuf in 64KB LDS. Each K/V b128 LDS read feeds TWO MFMAs
// (subtiles A,B) -> LDS read traffic per unit work halved vs 32-q-rows/wave.
// QK split into two sequential 32-k-row passes so only 2 f32x16 S-accs live.
// Grid (N/256, B, SEG=8) = 512 blocks -> 2 blocks/CU (LDS-capped).
// ---------------------------------------------------------------------------
template<int SEG, int TPS>
__global__ __launch_bounds__(256, 2) void attn_kernel(
    const bf16* __restrict__ qf_, const bf16* __restrict__ kf_,
    const bf16* __restrict__ vf_,
    bf16* __restrict__ Opar, float* __restrict__ lpar)
{
  __shared__ bf16 Kb[2][8192];   // [chunk 2][ks 8][64][8] per 64-row tile
  __shared__ bf16 Vb[2][8192];   // [chunk 2][dtile 4][ks2 2][64][8]

  const int tid  = threadIdx.x;
  const int lane = tid & 63;
  const int w    = tid >> 6;
  const int l31  = lane & 31;
  const int b    = blockIdx.y;
  const int seg  = blockIdx.z;
  const int q0w  = blockIdx.x * 256 + w * 64;   // wave's 64 q-rows

  // Q fragments for both subtiles (B operand of S^T = K Q^T)
  bf16x8 qfA[8], qfB[8];
  {
    const bf16* qb = qf_ + ((size_t)(b * 128 + (q0w >> 5))) * 4096 + lane * 8;
    #pragma unroll
    for (int ks = 0; ks < 8; ++ks) {
      qfA[ks] = *(const bf16x8*)(qb + ks * 512);
      qfB[ks] = *(const bf16x8*)(qb + 4096 + ks * 512);
    }
  }

  const bf16* ks_p = kf_ + (size_t)b * 128 * 4096 + (size_t)(seg * TPS) * 8192 + tid * 8;
  const bf16* vs_p = vf_ + (size_t)b * 128 * 4096 + (size_t)(seg * TPS) * 8192 + tid * 8;

  // prologue: stage tile 0 into buffer 0 (4 x 4KB rounds each for K, V)
  #pragma unroll
  for (int pp = 0; pp < 4; ++pp) {
    gld_lds16(ks_p + pp * 2048, &Kb[0][pp * 2048 + tid * 8]);
    gld_lds16(vs_p + pp * 2048, &Vb[0][pp * 2048 + tid * 8]);
  }
  __syncthreads();

  f32x16 oA[4], oB[4];
  #pragma unroll
  for (int dt = 0; dt < 4; ++dt)
    #pragma unroll
    for (int r = 0; r < 16; ++r) { oA[dt][r] = 0.f; oB[dt][r] = 0.f; }
  float lsumA = 0.f, lsumB = 0.f;

  for (int t = 0; t < TPS; ++t) {
    const int cur = t & 1;
    // ---- issue next tile's DMA (overlaps with this tile's compute)
    if (t + 1 < TPS) {
      const bf16* ksn = ks_p + (size_t)(t + 1) * 8192;
      const bf16* vsn = vs_p + (size_t)(t + 1) * 8192;
      #pragma unroll
      for (int pp = 0; pp < 4; ++pp) {
        gld_lds16(ksn + pp * 2048, &Kb[cur ^ 1][pp * 2048 + tid * 8]);
        gld_lds16(vsn + pp * 2048, &Vb[cur ^ 1][pp * 2048 + tid * 8]);
      }
    }
    const bf16* Kc = Kb[cur];
    const bf16* Vc = Vb[cur];

    // ---- two 32-k-row passes over the 64-row tile
    #pragma unroll
    for (int mt = 0; mt < 2; ++mt) {
      const bf16* Km = Kc + mt * 4096;
      const bf16* Vm = Vc + mt * 4096;

      // S^T = K Q^T for both q-subtiles: one K read -> two MFMAs
      f32x16 sA, sB;
      #pragma unroll
      for (int r = 0; r < 16; ++r) { sA[r] = 0.f; sB[r] = 0.f; }
      __builtin_amdgcn_s_setprio(1);
      #pragma unroll
      for (int ks = 0; ks < 8; ++ks) {
        bf16x8 k = *(const bf16x8*)&Km[(ks * 64 + lane) * 8];
        sA = mfma32(k, qfA[ks], sA);
        sB = mfma32(k, qfB[ks], sB);
      }
      __builtin_amdgcn_s_setprio(0);

      // p = exp2(S' - SHIFT2); VALU l partial; pack+permlane -> P fragments
      bf16x8 pA0, pA1, pB0, pB1;
      exp_pack(sA, lsumA, pA0, pA1);
      exp_pack(sB, lsumB, pB0, pB1);

      // PV: one V read -> two MFMAs
      __builtin_amdgcn_s_setprio(1);
      #pragma unroll
      for (int dt = 0; dt < 4; ++dt) {
        bf16x8 v = *(const bf16x8*)&Vm[((dt * 2 + 0) * 64 + lane) * 8];
        oA[dt] = mfma32(v, pA0, oA[dt]);
        oB[dt] = mfma32(v, pB0, oB[dt]);
      }
      #pragma unroll
      for (int dt = 0; dt < 4; ++dt) {
        bf16x8 v = *(const bf16x8*)&Vm[((dt * 2 + 1) * 64 + lane) * 8];
        oA[dt] = mfma32(v, pA1, oA[dt]);
        oB[dt] = mfma32(v, pB1, oB[dt]);
      }
      __builtin_amdgcn_s_setprio(0);
    }

    // one barrier per tile: drains next-tile DMA, protects buffers
    __syncthreads();
  }

  // ---- l: merge lane-halves, store per q-subtile
  {
    uint32_t a = __builtin_bit_cast(uint32_t, lsumA), a2 = a;
    pl32swap(a, a2);
    float lfA = __builtin_bit_cast(float, a) + __builtin_bit_cast(float, a2);
    uint32_t c = __builtin_bit_cast(uint32_t, lsumB), c2 = c;
    pl32swap(c, c2);
    float lfB = __builtin_bit_cast(float, c) + __builtin_bit_cast(float, c2);
    if (lane < 32) {
      lpar[((size_t)seg * B_ + b) * N_ + q0w + lane] = lfA;
      lpar[((size_t)seg * B_ + b) * N_ + q0w + 32 + lane] = lfB;
    }
  }

  // ---- store O^T partials (bf16): col=q=l31, row d = dt*32+R*8+4*(lane>>5)+i
  const int hh = lane >> 5;
  bf16* opA = Opar + (((size_t)seg * B_ + b) * N_ + q0w + l31) * C2_;
  bf16* opB = opA + (size_t)32 * C2_;
  #pragma unroll
  for (int dt = 0; dt < 4; ++dt) {
    #pragma unroll
    for (int R = 0; R < 4; ++R) {
      bf16x4 va, vb;
      #pragma unroll
      for (int i = 0; i < 4; ++i) {
        va[i] = (bf16)oA[dt][4 * R + i];
        vb[i] = (bf16)oB[dt][4 * R + i];
      }
      *(bf16x4*)(opA + dt * 32 + R * 8 + hh * 4) = va;
      *(bf16x4*)(opB + dt * 32 + R * 8 + hh * 4) = vb;
    }
  }
}

// ---------------------------------------------------------------------------
// Kernel 3: fused combine + final conv + residual.
// ---------------------------------------------------------------------------
template<int SEG>
__global__ __launch_bounds__(256) void final_kernel(
    const float* __restrict__ x, const float* __restrict__ wf,
    const float* __restrict__ bf_,
    const bf16* __restrict__ Opar, const float* __restrict__ lpar,
    float* __restrict__ out)
{
  __shared__ bf16 Ys[64][C2_ + 8];
  __shared__ float Linv[64];

  const int tid  = threadIdx.x;
  const int lane = tid & 63;
  const int w    = tid >> 6;
  const int n0   = blockIdx.x * 64;
  const int b    = blockIdx.y;
  const int l15  = lane & 15;
  const int lg   = lane >> 4;
  const int kbase = lg * 8;

  // ---- 1/l per row
  if (tid < 64) {
    float l = 0.f;
    #pragma unroll
    for (int s = 0; s < SEG; ++s)
      l += lpar[((size_t)s * B_ + b) * N_ + n0 + tid];
    Linv[tid] = 1.f / l;
  }
  __syncthreads();

  // ---- stage y tile (sum bf16 segs in f32, normalize, repack bf16)
  #pragma unroll
  for (int it = 0; it < 4; ++it) {
    int idx = it * 256 + tid;          // 0..1023 chunks of 8
    int r   = idx >> 4;
    int c8  = (idx & 15) * 8;
    float a[8] = {0.f, 0.f, 0.f, 0.f, 0.f, 0.f, 0.f, 0.f};
    #pragma unroll
    for (int s = 0; s < SEG; ++s) {
      bf16x8 v = *(const bf16x8*)(Opar
          + (((size_t)s * B_ + b) * N_ + n0 + r) * C2_ + c8);
      #pragma unroll
      for (int j = 0; j < 8; ++j) a[j] += (float)v[j];
    }
    float inv = Linv[r];
    bf16x8 y;
    #pragma unroll
    for (int j = 0; j < 8; ++j) y[j] = (bf16)(a[j] * inv);
    *(bf16x8*)&Ys[r][c8] = y;
  }
  __syncthreads();

  // ---- GEMM: wave w owns c-rows [64w, 64w+64)
  const f32x4 fzero = {0.f, 0.f, 0.f, 0.f};
  f32x4 acc[4][4];
  #pragma unroll
  for (int rt = 0; rt < 4; ++rt)
    #pragma unroll
    for (int ct = 0; ct < 4; ++ct) acc[rt][ct] = fzero;

  for (int kc = 0; kc < 4; ++kc) {
    bf16x8 bfr[4];
    #pragma unroll
    for (int ct = 0; ct < 4; ++ct)
      bfr[ct] = *(const bf16x8*)&Ys[ct * 16 + l15][kc * 32 + kbase];
    #pragma unroll
    for (int rt = 0; rt < 4; ++rt) {
      const float* wr = wf + (size_t)(w * 64 + rt * 16 + l15) * C2_ + kc * 32 + kbase;
      f32x4 lo = *(const f32x4*)wr;
      f32x4 hi = *(const f32x4*)(wr + 4);
      bf16x8 af;
      #pragma unroll
      for (int i = 0; i < 4; ++i) { af[i] = (bf16)lo[i]; af[4 + i] = (bf16)hi[i]; }
      #pragma unroll
      for (int ct = 0; ct < 4; ++ct)
        acc[rt][ct] = mfma16(af, bfr[ct], acc[rt][ct]);
    }
  }

  #pragma unroll
  for (int rt = 0; rt < 4; ++rt) {
    int cbase = w * 64 + rt * 16 + lg * 4;
    #pragma unroll
    for (int j = 0; j < 4; ++j) {
      float bias = bf_[cbase + j];
      #pragma unroll
      for (int ct = 0; ct < 4; ++ct) {
        int n = n0 + ct * 16 + l15;
        size_t idx = ((size_t)b * C_ + cbase + j) * N_ + n;
        out[idx] = x[idx] + bias + acc[rt][ct][j];
      }
    }
  }
}

// ---------------------------------------------------------------------------
extern "C" void kernel_launch(void* const* d_in, const int* in_sizes, int n_in,
                              void* d_out, int out_size, void* d_ws, size_t ws_size,
                              hipStream_t stream) {
  const float* x       = (const float*)d_in[0];
  const float* w_theta = (const float*)d_in[1];
  const float* b_theta = (const float*)d_in[2];
  const float* w_phi   = (const float*)d_in[3];
  const float* b_phi   = (const float*)d_in[4];
  const float* w_g     = (const float*)d_in[5];
  const float* b_g     = (const float*)d_in[6];
  const float* w_final = (const float*)d_in[7];
  const float* b_final = (const float*)d_in[8];
  float* out = (float*)d_out;

  char* ws = (char*)d_ws;
  const size_t SZB = (size_t)B_ * N_ * C2_ * sizeof(bf16);   // 4 MB each
  bf16*  th = (bf16*)(ws);
  bf16*  ph = (bf16*)(ws + SZB);
  bf16*  gt = (bf16*)(ws + 2 * SZB);
  bf16*  OparB = (bf16*)(ws + 3 * SZB);                      // SEG x 4 MB (bf16)

  proj_kernel<<<dim3(N_ / 64, B_), 256, 0, stream>>>(
      x, w_theta, b_theta, w_phi, b_phi, w_g, b_g, th, ph, gt);

  const size_t need8 = 3 * SZB + 8 * SZB + (size_t)8 * B_ * N_ * sizeof(float);
  if (ws_size >= need8) {
    // SEG=8: grid 512 blocks, 2 blocks/CU; TPS = 8 tiles of 64 KV rows
    float* lpar = (float*)(ws + 3 * SZB + 8 * SZB);
    attn_kernel<8, N_ / 8 / 64><<<dim3(N_ / 256, B_, 8), 256, 0, stream>>>(
        th, ph, gt, OparB, lpar);
    final_kernel<8><<<dim3(N_ / 64, B_), 256, 0, stream>>>(
        x, w_final, b_final, OparB, lpar, out);
  } else {
    // fallback: SEG=4 (workspace-limited), same 64-row tiles
    float* lpar = (float*)(ws + 3 * SZB + 4 * SZB);
    attn_kernel<4, N_ / 4 / 64><<<dim3(N_ / 256, B_, 4), 256, 0, stream>>>(
        th, ph, gt, OparB, lpar);
    final_kernel<4><<<dim3(N_ / 64, B_), 256, 0, stream>>>(
        x, w_final, b_final, OparB, lpar, out);
  }
}

// Round 3
// 99.785 us; speedup vs baseline: 1.0214x; 1.0214x over previous
//
#include <hip/hip_runtime.h>

#define B_ 4
#define C_ 256
#define C2_ 128
#define N_ 4096
#define LOG2E_ 1.4426950408889634f
#define SHIFT2_ 43.28085122666891f   // 30 * log2(e); softmax in exp2 domain

typedef __bf16 bf16;
typedef __bf16 bf16x8 __attribute__((ext_vector_type(8)));
typedef __bf16 bf16x4 __attribute__((ext_vector_type(4)));
typedef __bf16 bf16x2 __attribute__((ext_vector_type(2)));
typedef float f32x4 __attribute__((ext_vector_type(4)));
typedef float f32x16 __attribute__((ext_vector_type(16)));
typedef unsigned int u32x4 __attribute__((ext_vector_type(4)));

__device__ __forceinline__ f32x4 mfma16(bf16x8 a, bf16x8 b, f32x4 c) {
  return __builtin_amdgcn_mfma_f32_16x16x32_bf16(a, b, c, 0, 0, 0);
}
__device__ __forceinline__ f32x16 mfma32(bf16x8 a, bf16x8 b, f32x16 c) {
  return __builtin_amdgcn_mfma_f32_32x32x16_bf16(a, b, c, 0, 0, 0);
}

__device__ __forceinline__ float fexp2(float x) {
#if __has_builtin(__builtin_amdgcn_exp2f)
  return __builtin_amdgcn_exp2f(x);
#else
  return exp2f(x);
#endif
}

// async global->LDS, 16B per lane (dest = wave-uniform base + lane*16)
typedef const __attribute__((address_space(1))) uint32_t* gas_ptr;
typedef __attribute__((address_space(3))) uint32_t* las_ptr;
__device__ __forceinline__ void gld_lds16(const bf16* g, bf16* l) {
  __builtin_amdgcn_global_load_lds((gas_ptr)g, (las_ptr)l, 16, 0, 0);
}

// pack two f32 -> one dword of 2 bf16
__device__ __forceinline__ uint32_t pk2(float a, float b) {
  bf16x2 v; v[0] = (bf16)a; v[1] = (bf16)b;
  return __builtin_bit_cast(uint32_t, v);
}
// v_permlane32_swap_b32: a[l>=32] <-> b[l<32]  (VALU cross-lane, no LDS pipe)
__device__ __forceinline__ void pl32swap(uint32_t& a, uint32_t& b) {
  asm volatile("v_permlane32_swap_b32 %0, %1" : "+v"(a), "+v"(b));
}

// exp2-domain softmax numerator + VALU row-sum partial + bf16 pack/transpose
__device__ __forceinline__ void exp_pack(const f32x16& s, float& lsum,
                                         bf16x8& pf0, bf16x8& pf1) {
  float p[16];
  #pragma unroll
  for (int r = 0; r < 16; ++r) p[r] = fexp2(s[r] - SHIFT2_);
  float a0 = (p[0] + p[1]) + (p[2] + p[3]);
  float a1 = (p[4] + p[5]) + (p[6] + p[7]);
  float a2 = (p[8] + p[9]) + (p[10] + p[11]);
  float a3 = (p[12] + p[13]) + (p[14] + p[15]);
  lsum += (a0 + a1) + (a2 + a3);
  uint32_t A[4], Bb[4];
  #pragma unroll
  for (int G = 0; G < 4; ++G) {
    A[G]  = pk2(p[4 * G + 0], p[4 * G + 1]);
    Bb[G] = pk2(p[4 * G + 2], p[4 * G + 3]);
  }
  pl32swap(A[0], A[1]);  pl32swap(Bb[0], Bb[1]);
  { u32x4 dv = {A[0], Bb[0], A[1], Bb[1]}; pf0 = __builtin_bit_cast(bf16x8, dv); }
  pl32swap(A[2], A[3]);  pl32swap(Bb[2], Bb[3]);
  { u32x4 dv = {A[2], Bb[2], A[3], Bb[3]}; pf1 = __builtin_bit_cast(bf16x8, dv); }
}

// 32x32x16 fragment layouts:
//  A/B: lane = idx%32 + 32*((k%16)/8), elem = k%8 (8 bf16 / 4 VGPRs)
//  C/D: col = lane&31, row = (reg&3) + 8*(reg>>2) + 4*(lane>>5)
// Operand storage (fragment-major, wave reads = linear 1KB):
//  theta/phi: [b][n/32][ks 8][64][8]   (theta pre-scaled by log2e)
//  g (V^T):   [b][n/32 chunk][dtile 4][ks2 2][64][8] (8KB per 32-row chunk)

// ---------------------------------------------------------------------------
// Kernel 1: fused 3-way 1x1-conv projections, fragment-major outputs.
// ---------------------------------------------------------------------------
__global__ __launch_bounds__(256) void proj_kernel(
    const float* __restrict__ x,
    const float* __restrict__ w0, const float* __restrict__ b0,
    const float* __restrict__ w1, const float* __restrict__ b1,
    const float* __restrict__ w2, const float* __restrict__ b2,
    bf16* __restrict__ o0, bf16* __restrict__ o1, bf16* __restrict__ o2)
{
  __shared__ bf16 Xs[64][C_];   // [n][c], 16B block cb swizzled: cb ^= (n&7)
  const int tid  = threadIdx.x;
  const int lane = tid & 63;
  const int w    = tid >> 6;
  const int n0   = blockIdx.x * 64;
  const int b    = blockIdx.y;
  const int l15  = lane & 15;
  const int lg   = lane >> 4;
  const float* xb = x + (size_t)b * C_ * N_;

  // stage X^T: thread owns row n=lane, wave w covers c in [64w, 64w+64)
  {
    const int nl = lane;
    #pragma unroll
    for (int g = 0; g < 8; ++g) {
      int c0 = w * 64 + g * 8;
      bf16x8 h;
      #pragma unroll
      for (int i = 0; i < 8; ++i)
        h[i] = (bf16)xb[(size_t)(c0 + i) * N_ + n0 + nl];
      int cbs = (c0 >> 3) ^ (nl & 7);
      *(bf16x8*)&Xs[nl][cbs * 8] = h;
    }
  }
  __syncthreads();

  const f32x4 fzero = {0.f, 0.f, 0.f, 0.f};
  f32x4 acc[3][2][4];
  #pragma unroll
  for (int p = 0; p < 3; ++p)
    #pragma unroll
    for (int ot = 0; ot < 2; ++ot)
      #pragma unroll
      for (int nt = 0; nt < 4; ++nt) acc[p][ot][nt] = fzero;

  const float* Wp[3] = {w0, w1, w2};
  const int arow = w * 32 + l15;
  const int kbase = lg * 8;

  for (int kc = 0; kc < 8; ++kc) {
    bf16x8 bfr[4];
    #pragma unroll
    for (int nt = 0; nt < 4; ++nt) {
      int n = nt * 16 + l15;
      int cbs = (kc * 4 + lg) ^ (n & 7);
      bfr[nt] = *(const bf16x8*)&Xs[n][cbs * 8];
    }
    #pragma unroll
    for (int p = 0; p < 3; ++p) {
      #pragma unroll
      for (int ot = 0; ot < 2; ++ot) {
        const float* wr = Wp[p] + (size_t)(arow + ot * 16) * C_ + kc * 32 + kbase;
        f32x4 lo = *(const f32x4*)wr;
        f32x4 hi = *(const f32x4*)(wr + 4);
        bf16x8 af;
        if (p == 0) {
          #pragma unroll
          for (int i = 0; i < 4; ++i) {
            af[i]     = (bf16)(lo[i] * LOG2E_);
            af[4 + i] = (bf16)(hi[i] * LOG2E_);
          }
        } else {
          #pragma unroll
          for (int i = 0; i < 4; ++i) { af[i] = (bf16)lo[i]; af[4 + i] = (bf16)hi[i]; }
        }
        #pragma unroll
        for (int nt = 0; nt < 4; ++nt)
          acc[p][ot][nt] = mfma16(af, bfr[nt], acc[p][ot][nt]);
      }
    }
  }

  // ---- theta (p=0, log2e-scaled), phi (p=1): [b][n/32][ks 8][64][8]
  const float* Bp[3] = {b0, b1, b2};
  bf16* Op2[2] = {o0, o1};
  #pragma unroll
  for (int p = 0; p < 2; ++p) {
    bf16* dst = Op2[p] + (size_t)b * 128 * 8 * 512;
    #pragma unroll
    for (int ot = 0; ot < 2; ++ot) {
      int ks = w * 2 + ot;            // c>>4 (c = w*32+ot*16+lg*4+j)
      float bv[4];
      #pragma unroll
      for (int j = 0; j < 4; ++j) {
        float t = Bp[p][w * 32 + ot * 16 + lg * 4 + j];
        bv[j] = (p == 0) ? t * LOG2E_ : t;
      }
      #pragma unroll
      for (int nt = 0; nt < 4; ++nt) {
        int qtile = (n0 >> 5) + (nt >> 1);
        int lanep = ((nt & 1) * 16 + l15) + 32 * (lg >> 1);
        int elemb = (lg & 1) * 4;
        bf16x4 ov;
        #pragma unroll
        for (int j = 0; j < 4; ++j) ov[j] = (bf16)(acc[p][ot][nt][j] + bv[j]);
        *(bf16x4*)(dst + ((size_t)(qtile * 8 + ks) * 64 + lanep) * 8 + elemb) = ov;
      }
    }
  }
  // ---- g (p=2): [b][n/32 chunk][dtile 4][ks2 2][64][8]  (8KB per chunk)
  {
    bf16* dst = o2 + (size_t)b * 128 * 4096;
    const int t32b = n0 >> 5;
    #pragma unroll
    for (int ot = 0; ot < 2; ++ot) {
      #pragma unroll
      for (int j = 0; j < 4; ++j) {
        float bv = b2[w * 32 + ot * 16 + lg * 4 + j];
        int d31 = ot * 16 + lg * 4 + j;        // d&31 (dtile = w)
        #pragma unroll
        for (int nt = 0; nt < 4; ++nt) {
          int t32 = t32b + (nt >> 1);          // 32-row chunk index
          int ks2 = nt & 1;                    // 16-row k-slice within chunk
          int lanep = d31 + 32 * (l15 >> 3);
          dst[((size_t)((t32 * 4 + w) * 2 + ks2) * 64 + lanep) * 8 + (l15 & 7)] =
              (bf16)(acc[2][ot][nt][j] + bv);
        }
      }
    }
  }
}

// ---------------------------------------------------------------------------
// Kernel 2: flash attention. 512 thr (8 waves), wave = 32 q-rows (block=256),
// 64-row KV tiles dbuf in 64KB LDS via global_load_lds, ONE barrier per tile.
// Per-wave register content = round-1's proven no-spill budget (o_acc in
// AGPR, single S chain): combined ~128 regs -> 4 waves/SIMD at 2 blocks/CU.
// Overhead density: 1 barrier / (64 KV x 256 q) = half of round 0.
// Grid (N/256, B, SEG=8) = 512 blocks.
// ---------------------------------------------------------------------------
template<int SEG, int TPS>
__global__ __launch_bounds__(512, 4) void attn_kernel(
    const bf16* __restrict__ qf_, const bf16* __restrict__ kf_,
    const bf16* __restrict__ vf_,
    bf16* __restrict__ Opar, float* __restrict__ lpar)
{
  __shared__ bf16 Kb[2][8192];   // [chunk 2][ks 8][64][8] per 64-row tile
  __shared__ bf16 Vb[2][8192];   // [chunk 2][dtile 4][ks2 2][64][8]

  const int tid  = threadIdx.x;
  const int lane = tid & 63;
  const int w    = tid >> 6;       // 0..7
  const int l31  = lane & 31;
  const int b    = blockIdx.y;
  const int seg  = blockIdx.z;
  const int q0w  = blockIdx.x * 256 + w * 32;   // wave's 32 q-rows

  // Q fragments (B operand of S^T = K Q^T): 8 coalesced 1KB loads
  bf16x8 qf[8];
  {
    const bf16* qb = qf_ + ((size_t)(b * 128 + (q0w >> 5))) * 4096 + lane * 8;
    #pragma unroll
    for (int ks = 0; ks < 8; ++ks)
      qf[ks] = *(const bf16x8*)(qb + ks * 512);
  }

  const bf16* ks_p = kf_ + (size_t)b * 128 * 4096 + (size_t)(seg * TPS) * 8192 + tid * 8;
  const bf16* vs_p = vf_ + (size_t)b * 128 * 4096 + (size_t)(seg * TPS) * 8192 + tid * 8;

  // prologue: stage tile 0 into buffer 0 (512 thr x 16B = 8KB per call)
  #pragma unroll
  for (int pp = 0; pp < 2; ++pp) {
    gld_lds16(ks_p + pp * 4096, &Kb[0][pp * 4096 + tid * 8]);
    gld_lds16(vs_p + pp * 4096, &Vb[0][pp * 4096 + tid * 8]);
  }
  __syncthreads();

  f32x16 o_acc[4];
  #pragma unroll
  for (int dt = 0; dt < 4; ++dt)
    #pragma unroll
    for (int r = 0; r < 16; ++r) o_acc[dt][r] = 0.f;
  float lsum = 0.f;   // this lane-half's partial row sum (q = l31)

  for (int t = 0; t < TPS; ++t) {
    const int cur = t & 1;
    // ---- issue next tile's DMA (overlaps with this tile's compute)
    if (t + 1 < TPS) {
      const bf16* ksn = ks_p + (size_t)(t + 1) * 8192;
      const bf16* vsn = vs_p + (size_t)(t + 1) * 8192;
      #pragma unroll
      for (int pp = 0; pp < 2; ++pp) {
        gld_lds16(ksn + pp * 4096, &Kb[cur ^ 1][pp * 4096 + tid * 8]);
        gld_lds16(vsn + pp * 4096, &Vb[cur ^ 1][pp * 4096 + tid * 8]);
      }
    }
    const bf16* Kc = Kb[cur];
    const bf16* Vc = Vb[cur];

    // ---- two 32-k-row passes over the 64-row tile (single S chain each:
    // keeps live regs at the round-1 no-spill level; 4 waves/SIMD hide dep)
    #pragma unroll
    for (int mt = 0; mt < 2; ++mt) {
      const bf16* Km = Kc + mt * 4096;
      const bf16* Vm = Vc + mt * 4096;

      f32x16 s;
      #pragma unroll
      for (int r = 0; r < 16; ++r) s[r] = 0.f;
      __builtin_amdgcn_s_setprio(1);
      #pragma unroll
      for (int ks = 0; ks < 8; ++ks) {
        bf16x8 k = *(const bf16x8*)&Km[(ks * 64 + lane) * 8];
        s = mfma32(k, qf[ks], s);
      }
      __builtin_amdgcn_s_setprio(0);

      bf16x8 pf0, pf1;
      exp_pack(s, lsum, pf0, pf1);

      __builtin_amdgcn_s_setprio(1);
      #pragma unroll
      for (int dt = 0; dt < 4; ++dt) {
        bf16x8 v = *(const bf16x8*)&Vm[((dt * 2 + 0) * 64 + lane) * 8];
        o_acc[dt] = mfma32(v, pf0, o_acc[dt]);
      }
      #pragma unroll
      for (int dt = 0; dt < 4; ++dt) {
        bf16x8 v = *(const bf16x8*)&Vm[((dt * 2 + 1) * 64 + lane) * 8];
        o_acc[dt] = mfma32(v, pf1, o_acc[dt]);
      }
      __builtin_amdgcn_s_setprio(0);
    }

    // one barrier per tile: drains next-tile DMA, protects buffers
    __syncthreads();
  }

  // ---- l: merge lane-halves (each lane summed its half's 32 k-rows/tile)
  {
    uint32_t a = __builtin_bit_cast(uint32_t, lsum), a2 = a;
    pl32swap(a, a2);
    float lf = __builtin_bit_cast(float, a) + __builtin_bit_cast(float, a2);
    if (lane < 32)
      lpar[((size_t)seg * B_ + b) * N_ + q0w + lane] = lf;
  }

  // ---- store O^T partials (bf16): col=q=l31, row d = dt*32+R*8+4*(lane>>5)+i
  const int hh = lane >> 5;
  bf16* op = Opar + (((size_t)seg * B_ + b) * N_ + q0w + l31) * C2_;
  #pragma unroll
  for (int dt = 0; dt < 4; ++dt) {
    #pragma unroll
    for (int R = 0; R < 4; ++R) {
      bf16x4 v;
      #pragma unroll
      for (int i = 0; i < 4; ++i) v[i] = (bf16)o_acc[dt][4 * R + i];
      *(bf16x4*)(op + dt * 32 + R * 8 + hh * 4) = v;
    }
  }
}

// ---------------------------------------------------------------------------
// Kernel 3: fused combine + final conv + residual.
// ---------------------------------------------------------------------------
template<int SEG>
__global__ __launch_bounds__(256) void final_kernel(
    const float* __restrict__ x, const float* __restrict__ wf,
    const float* __restrict__ bf_,
    const bf16* __restrict__ Opar, const float* __restrict__ lpar,
    float* __restrict__ out)
{
  __shared__ bf16 Ys[64][C2_ + 8];
  __shared__ float Linv[64];

  const int tid  = threadIdx.x;
  const int lane = tid & 63;
  const int w    = tid >> 6;
  const int n0   = blockIdx.x * 64;
  const int b    = blockIdx.y;
  const int l15  = lane & 15;
  const int lg   = lane >> 4;
  const int kbase = lg * 8;

  // ---- 1/l per row
  if (tid < 64) {
    float l = 0.f;
    #pragma unroll
    for (int s = 0; s < SEG; ++s)
      l += lpar[((size_t)s * B_ + b) * N_ + n0 + tid];
    Linv[tid] = 1.f / l;
  }
  __syncthreads();

  // ---- stage y tile (sum bf16 segs in f32, normalize, repack bf16)
  #pragma unroll
  for (int it = 0; it < 4; ++it) {
    int idx = it * 256 + tid;          // 0..1023 chunks of 8
    int r   = idx >> 4;
    int c8  = (idx & 15) * 8;
    float a[8] = {0.f, 0.f, 0.f, 0.f, 0.f, 0.f, 0.f, 0.f};
    #pragma unroll
    for (int s = 0; s < SEG; ++s) {
      bf16x8 v = *(const bf16x8*)(Opar
          + (((size_t)s * B_ + b) * N_ + n0 + r) * C2_ + c8);
      #pragma unroll
      for (int j = 0; j < 8; ++j) a[j] += (float)v[j];
    }
    float inv = Linv[r];
    bf16x8 y;
    #pragma unroll
    for (int j = 0; j < 8; ++j) y[j] = (bf16)(a[j] * inv);
    *(bf16x8*)&Ys[r][c8] = y;
  }
  __syncthreads();

  // ---- GEMM: wave w owns c-rows [64w, 64w+64)
  const f32x4 fzero = {0.f, 0.f, 0.f, 0.f};
  f32x4 acc[4][4];
  #pragma unroll
  for (int rt = 0; rt < 4; ++rt)
    #pragma unroll
    for (int ct = 0; ct < 4; ++ct) acc[rt][ct] = fzero;

  for (int kc = 0; kc < 4; ++kc) {
    bf16x8 bfr[4];
    #pragma unroll
    for (int ct = 0; ct < 4; ++ct)
      bfr[ct] = *(const bf16x8*)&Ys[ct * 16 + l15][kc * 32 + kbase];
    #pragma unroll
    for (int rt = 0; rt < 4; ++rt) {
      const float* wr = wf + (size_t)(w * 64 + rt * 16 + l15) * C2_ + kc * 32 + kbase;
      f32x4 lo = *(const f32x4*)wr;
      f32x4 hi = *(const f32x4*)(wr + 4);
      bf16x8 af;
      #pragma unroll
      for (int i = 0; i < 4; ++i) { af[i] = (bf16)lo[i]; af[4 + i] = (bf16)hi[i]; }
      #pragma unroll
      for (int ct = 0; ct < 4; ++ct)
        acc[rt][ct] = mfma16(af, bfr[ct], acc[rt][ct]);
    }
  }

  #pragma unroll
  for (int rt = 0; rt < 4; ++rt) {
    int cbase = w * 64 + rt * 16 + lg * 4;
    #pragma unroll
    for (int j = 0; j < 4; ++j) {
      float bias = bf_[cbase + j];
      #pragma unroll
      for (int ct = 0; ct < 4; ++ct) {
        int n = n0 + ct * 16 + l15;
        size_t idx = ((size_t)b * C_ + cbase + j) * N_ + n;
        out[idx] = x[idx] + bias + acc[rt][ct][j];
      }
    }
  }
}

// ---------------------------------------------------------------------------
extern "C" void kernel_launch(void* const* d_in, const int* in_sizes, int n_in,
                              void* d_out, int out_size, void* d_ws, size_t ws_size,
                              hipStream_t stream) {
  const float* x       = (const float*)d_in[0];
  const float* w_theta = (const float*)d_in[1];
  const float* b_theta = (const float*)d_in[2];
  const float* w_phi   = (const float*)d_in[3];
  const float* b_phi   = (const float*)d_in[4];
  const float* w_g     = (const float*)d_in[5];
  const float* b_g     = (const float*)d_in[6];
  const float* w_final = (const float*)d_in[7];
  const float* b_final = (const float*)d_in[8];
  float* out = (float*)d_out;

  char* ws = (char*)d_ws;
  const size_t SZB = (size_t)B_ * N_ * C2_ * sizeof(bf16);   // 4 MB each
  bf16*  th = (bf16*)(ws);
  bf16*  ph = (bf16*)(ws + SZB);
  bf16*  gt = (bf16*)(ws + 2 * SZB);
  bf16*  OparB = (bf16*)(ws + 3 * SZB);                      // SEG x 4 MB (bf16)

  proj_kernel<<<dim3(N_ / 64, B_), 256, 0, stream>>>(
      x, w_theta, b_theta, w_phi, b_phi, w_g, b_g, th, ph, gt);

  const size_t need8 = 3 * SZB + 8 * SZB + (size_t)8 * B_ * N_ * sizeof(float);
  if (ws_size >= need8) {
    // SEG=8: 512 blocks of 512 thr -> 2 blocks/CU, 4 waves/SIMD; TPS=8
    float* lpar = (float*)(ws + 3 * SZB + 8 * SZB);
    attn_kernel<8, N_ / 8 / 64><<<dim3(N_ / 256, B_, 8), 512, 0, stream>>>(
        th, ph, gt, OparB, lpar);
    final_kernel<8><<<dim3(N_ / 64, B_), 256, 0, stream>>>(
        x, w_final, b_final, OparB, lpar, out);
  } else {
    // fallback: SEG=4 (workspace-limited), same 64-row tiles
    float* lpar = (float*)(ws + 3 * SZB + 4 * SZB);
    attn_kernel<4, N_ / 4 / 64><<<dim3(N_ / 256, B_, 4), 512, 0, stream>>>(
        th, ph, gt, OparB, lpar);
    final_kernel<4><<<dim3(N_ / 64, B_), 256, 0, stream>>>(
        x, w_final, b_final, OparB, lpar, out);
  }
}

// Round 4
// 87.674 us; speedup vs baseline: 1.1625x; 1.1381x over previous
//
#include <hip/hip_runtime.h>

#define B_ 4
#define C_ 256
#define C2_ 128
#define N_ 4096
#define LOG2E_ 1.4426950408889634f
#define SHIFT2_ 43.28085122666891f   // 30 * log2(e); softmax in exp2 domain

typedef __bf16 bf16;
typedef __bf16 bf16x8 __attribute__((ext_vector_type(8)));
typedef __bf16 bf16x4 __attribute__((ext_vector_type(4)));
typedef __bf16 bf16x2 __attribute__((ext_vector_type(2)));
typedef float f32x4 __attribute__((ext_vector_type(4)));
typedef float f32x16 __attribute__((ext_vector_type(16)));
typedef unsigned int u32x4 __attribute__((ext_vector_type(4)));

__device__ __forceinline__ f32x4 mfma16(bf16x8 a, bf16x8 b, f32x4 c) {
  return __builtin_amdgcn_mfma_f32_16x16x32_bf16(a, b, c, 0, 0, 0);
}
__device__ __forceinline__ f32x16 mfma32(bf16x8 a, bf16x8 b, f32x16 c) {
  return __builtin_amdgcn_mfma_f32_32x32x16_bf16(a, b, c, 0, 0, 0);
}

__device__ __forceinline__ float fexp2(float x) {
#if __has_builtin(__builtin_amdgcn_exp2f)
  return __builtin_amdgcn_exp2f(x);
#else
  return exp2f(x);
#endif
}

// async global->LDS, 16B per lane (dest = wave-uniform base + lane*16)
typedef const __attribute__((address_space(1))) uint32_t* gas_ptr;
typedef __attribute__((address_space(3))) uint32_t* las_ptr;
__device__ __forceinline__ void gld_lds16(const bf16* g, bf16* l) {
  __builtin_amdgcn_global_load_lds((gas_ptr)g, (las_ptr)l, 16, 0, 0);
}

// pack two f32 -> one dword of 2 bf16
__device__ __forceinline__ uint32_t pk2(float a, float b) {
  bf16x2 v; v[0] = (bf16)a; v[1] = (bf16)b;
  return __builtin_bit_cast(uint32_t, v);
}
// v_permlane32_swap_b32: a[l>=32] <-> b[l<32]  (VALU cross-lane, no LDS pipe)
__device__ __forceinline__ void pl32swap(uint32_t& a, uint32_t& b) {
  asm volatile("v_permlane32_swap_b32 %0, %1" : "+v"(a), "+v"(b));
}

// exp2-domain softmax numerator + VALU row-sum partial + bf16 pack/transpose
__device__ __forceinline__ void exp_pack(const f32x16& s, float& lsum,
                                         bf16x8& pf0, bf16x8& pf1) {
  float p[16];
  #pragma unroll
  for (int r = 0; r < 16; ++r) p[r] = fexp2(s[r] - SHIFT2_);
  float a0 = (p[0] + p[1]) + (p[2] + p[3]);
  float a1 = (p[4] + p[5]) + (p[6] + p[7]);
  float a2 = (p[8] + p[9]) + (p[10] + p[11]);
  float a3 = (p[12] + p[13]) + (p[14] + p[15]);
  lsum += (a0 + a1) + (a2 + a3);
  uint32_t A[4], Bb[4];
  #pragma unroll
  for (int G = 0; G < 4; ++G) {
    A[G]  = pk2(p[4 * G + 0], p[4 * G + 1]);
    Bb[G] = pk2(p[4 * G + 2], p[4 * G + 3]);
  }
  pl32swap(A[0], A[1]);  pl32swap(Bb[0], Bb[1]);
  { u32x4 dv = {A[0], Bb[0], A[1], Bb[1]}; pf0 = __builtin_bit_cast(bf16x8, dv); }
  pl32swap(A[2], A[3]);  pl32swap(Bb[2], Bb[3]);
  { u32x4 dv = {A[2], Bb[2], A[3], Bb[3]}; pf1 = __builtin_bit_cast(bf16x8, dv); }
}

// 32x32x16 fragment layouts:
//  A/B: lane = idx%32 + 32*((k%16)/8), elem = k%8 (8 bf16 / 4 VGPRs)
//  C/D: col = lane&31, row = (reg&3) + 8*(reg>>2) + 4*(lane>>5)
// Operand storage (fragment-major, wave reads = linear 1KB):
//  theta/phi: [b][n/32][ks 8][64][8]   (theta pre-scaled by log2e)
//  g (V^T):   [b][n/32 chunk][dtile 4][ks2 2][64][8] (8KB per 32-row chunk)

// ---------------------------------------------------------------------------
// Kernel 1: fused 3-way 1x1-conv projections, fragment-major outputs.
// ---------------------------------------------------------------------------
__global__ __launch_bounds__(256) void proj_kernel(
    const float* __restrict__ x,
    const float* __restrict__ w0, const float* __restrict__ b0,
    const float* __restrict__ w1, const float* __restrict__ b1,
    const float* __restrict__ w2, const float* __restrict__ b2,
    bf16* __restrict__ o0, bf16* __restrict__ o1, bf16* __restrict__ o2)
{
  __shared__ bf16 Xs[64][C_];   // [n][c], 16B block cb swizzled: cb ^= (n&7)
  const int tid  = threadIdx.x;
  const int lane = tid & 63;
  const int w    = tid >> 6;
  const int n0   = blockIdx.x * 64;
  const int b    = blockIdx.y;
  const int l15  = lane & 15;
  const int lg   = lane >> 4;
  const float* xb = x + (size_t)b * C_ * N_;

  // stage X^T: thread owns row n=lane, wave w covers c in [64w, 64w+64)
  {
    const int nl = lane;
    #pragma unroll
    for (int g = 0; g < 8; ++g) {
      int c0 = w * 64 + g * 8;
      bf16x8 h;
      #pragma unroll
      for (int i = 0; i < 8; ++i)
        h[i] = (bf16)xb[(size_t)(c0 + i) * N_ + n0 + nl];
      int cbs = (c0 >> 3) ^ (nl & 7);
      *(bf16x8*)&Xs[nl][cbs * 8] = h;
    }
  }
  __syncthreads();

  const f32x4 fzero = {0.f, 0.f, 0.f, 0.f};
  f32x4 acc[3][2][4];
  #pragma unroll
  for (int p = 0; p < 3; ++p)
    #pragma unroll
    for (int ot = 0; ot < 2; ++ot)
      #pragma unroll
      for (int nt = 0; nt < 4; ++nt) acc[p][ot][nt] = fzero;

  const float* Wp[3] = {w0, w1, w2};
  const int arow = w * 32 + l15;
  const int kbase = lg * 8;

  for (int kc = 0; kc < 8; ++kc) {
    bf16x8 bfr[4];
    #pragma unroll
    for (int nt = 0; nt < 4; ++nt) {
      int n = nt * 16 + l15;
      int cbs = (kc * 4 + lg) ^ (n & 7);
      bfr[nt] = *(const bf16x8*)&Xs[n][cbs * 8];
    }
    #pragma unroll
    for (int p = 0; p < 3; ++p) {
      #pragma unroll
      for (int ot = 0; ot < 2; ++ot) {
        const float* wr = Wp[p] + (size_t)(arow + ot * 16) * C_ + kc * 32 + kbase;
        f32x4 lo = *(const f32x4*)wr;
        f32x4 hi = *(const f32x4*)(wr + 4);
        bf16x8 af;
        if (p == 0) {
          #pragma unroll
          for (int i = 0; i < 4; ++i) {
            af[i]     = (bf16)(lo[i] * LOG2E_);
            af[4 + i] = (bf16)(hi[i] * LOG2E_);
          }
        } else {
          #pragma unroll
          for (int i = 0; i < 4; ++i) { af[i] = (bf16)lo[i]; af[4 + i] = (bf16)hi[i]; }
        }
        #pragma unroll
        for (int nt = 0; nt < 4; ++nt)
          acc[p][ot][nt] = mfma16(af, bfr[nt], acc[p][ot][nt]);
      }
    }
  }

  // ---- theta (p=0, log2e-scaled), phi (p=1): [b][n/32][ks 8][64][8]
  const float* Bp[3] = {b0, b1, b2};
  bf16* Op2[2] = {o0, o1};
  #pragma unroll
  for (int p = 0; p < 2; ++p) {
    bf16* dst = Op2[p] + (size_t)b * 128 * 8 * 512;
    #pragma unroll
    for (int ot = 0; ot < 2; ++ot) {
      int ks = w * 2 + ot;            // c>>4 (c = w*32+ot*16+lg*4+j)
      float bv[4];
      #pragma unroll
      for (int j = 0; j < 4; ++j) {
        float t = Bp[p][w * 32 + ot * 16 + lg * 4 + j];
        bv[j] = (p == 0) ? t * LOG2E_ : t;
      }
      #pragma unroll
      for (int nt = 0; nt < 4; ++nt) {
        int qtile = (n0 >> 5) + (nt >> 1);
        int lanep = ((nt & 1) * 16 + l15) + 32 * (lg >> 1);
        int elemb = (lg & 1) * 4;
        bf16x4 ov;
        #pragma unroll
        for (int j = 0; j < 4; ++j) ov[j] = (bf16)(acc[p][ot][nt][j] + bv[j]);
        *(bf16x4*)(dst + ((size_t)(qtile * 8 + ks) * 64 + lanep) * 8 + elemb) = ov;
      }
    }
  }
  // ---- g (p=2): [b][n/32 chunk][dtile 4][ks2 2][64][8]  (8KB per chunk)
  {
    bf16* dst = o2 + (size_t)b * 128 * 4096;
    const int t32b = n0 >> 5;
    #pragma unroll
    for (int ot = 0; ot < 2; ++ot) {
      #pragma unroll
      for (int j = 0; j < 4; ++j) {
        float bv = b2[w * 32 + ot * 16 + lg * 4 + j];
        int d31 = ot * 16 + lg * 4 + j;        // d&31 (dtile = w)
        #pragma unroll
        for (int nt = 0; nt < 4; ++nt) {
          int t32 = t32b + (nt >> 1);          // 32-row chunk index
          int ks2 = nt & 1;                    // 16-row k-slice within chunk
          int lanep = d31 + 32 * (l15 >> 3);
          dst[((size_t)((t32 * 4 + w) * 2 + ks2) * 64 + lanep) * 8 + (l15 & 7)] =
              (bf16)(acc[2][ot][nt][j] + bv);
        }
      }
    }
  }
}

// ---------------------------------------------------------------------------
// Kernel 2: flash attention. 256 thr (4 waves), wave = 32 q-rows, 64-row KV
// tiles. K staged in 32KB dbuf LDS via global_load_lds (halved vs before);
// V fragments read DIRECTLY from global (coalesced 1KB loads, L2-resident:
// each (b,seg) V slice = 128KB shared by 32 blocks) -- no V LDS, half the
// LDS-read pipe load, half the DMA drained per barrier. V frags for each
// 32-kv-row pass issued BEFORE its QK chain (latency hidden under MFMA).
// launch_bounds(256,3): reg cap 170 -> no spill; 3 blocks/CU, 12 waves/CU.
// ---------------------------------------------------------------------------
template<int SEG, int TPS>
__global__ __launch_bounds__(256, 3) void attn_kernel(
    const bf16* __restrict__ qf_, const bf16* __restrict__ kf_,
    const bf16* __restrict__ vf_,
    bf16* __restrict__ Opar, float* __restrict__ lpar)
{
  __shared__ bf16 Kb[2][8192];   // [chunk 2][ks 8][64][8] per 64-row K tile

  const int tid  = threadIdx.x;
  const int lane = tid & 63;
  const int w    = tid >> 6;       // 0..3
  const int l31  = lane & 31;
  const int b    = blockIdx.y;
  const int seg  = blockIdx.z;
  const int q0w  = blockIdx.x * 128 + w * 32;   // wave's 32 q-rows

  // Q fragments (B operand of S^T = K Q^T): 8 coalesced 1KB loads
  bf16x8 qf[8];
  {
    const bf16* qb = qf_ + ((size_t)(b * 128 + (q0w >> 5))) * 4096 + lane * 8;
    #pragma unroll
    for (int ks = 0; ks < 8; ++ks)
      qf[ks] = *(const bf16x8*)(qb + ks * 512);
  }

  const bf16* ks_p = kf_ + (size_t)b * 128 * 4096 + (size_t)(seg * TPS) * 8192 + tid * 8;
  const bf16* vs_b = vf_ + (size_t)b * 128 * 4096 + (size_t)(seg * TPS) * 8192 + lane * 8;

  // prologue: stage K tile 0 into buffer 0 (256 thr x 16B = 4KB per call)
  #pragma unroll
  for (int pp = 0; pp < 4; ++pp)
    gld_lds16(ks_p + pp * 2048, &Kb[0][pp * 2048 + tid * 8]);
  __syncthreads();

  f32x16 o_acc[4];
  #pragma unroll
  for (int dt = 0; dt < 4; ++dt)
    #pragma unroll
    for (int r = 0; r < 16; ++r) o_acc[dt][r] = 0.f;
  float lsum = 0.f;   // this lane-half's partial row sum (q = l31)

  for (int t = 0; t < TPS; ++t) {
    const int cur = t & 1;
    // ---- issue next K tile's DMA (overlaps with this tile's compute)
    if (t + 1 < TPS) {
      const bf16* ksn = ks_p + (size_t)(t + 1) * 8192;
      #pragma unroll
      for (int pp = 0; pp < 4; ++pp)
        gld_lds16(ksn + pp * 2048, &Kb[cur ^ 1][pp * 2048 + tid * 8]);
    }
    const bf16* Kc = Kb[cur];

    // ---- two 32-kv-row passes over the 64-row tile
    #pragma unroll
    for (int mt = 0; mt < 2; ++mt) {
      const bf16* Km = Kc + mt * 4096;
      const bf16* Vg = vs_b + (size_t)t * 8192 + mt * 4096;

      // prefetch V fragments from global/L2 (8 x 1KB coalesced; consumed
      // after QK+exp -> ~700cy of MFMA/VALU cover for L2 latency)
      bf16x8 vfr[8];
      #pragma unroll
      for (int i = 0; i < 8; ++i)
        vfr[i] = *(const bf16x8*)(Vg + i * 512);

      // S^T = K Q^T (exp2 domain): lane holds col q = l31
      f32x16 s;
      #pragma unroll
      for (int r = 0; r < 16; ++r) s[r] = 0.f;
      __builtin_amdgcn_s_setprio(1);
      #pragma unroll
      for (int ks = 0; ks < 8; ++ks) {
        bf16x8 k = *(const bf16x8*)&Km[(ks * 64 + lane) * 8];
        s = mfma32(k, qf[ks], s);
      }
      __builtin_amdgcn_s_setprio(0);

      bf16x8 pf0, pf1;
      exp_pack(s, lsum, pf0, pf1);

      // PV: V frag i = dt*2 + ks2
      __builtin_amdgcn_s_setprio(1);
      #pragma unroll
      for (int dt = 0; dt < 4; ++dt)
        o_acc[dt] = mfma32(vfr[dt * 2 + 0], pf0, o_acc[dt]);
      #pragma unroll
      for (int dt = 0; dt < 4; ++dt)
        o_acc[dt] = mfma32(vfr[dt * 2 + 1], pf1, o_acc[dt]);
      __builtin_amdgcn_s_setprio(0);
    }

    // one barrier per tile: drains next K-tile DMA, protects K buffers
    __syncthreads();
  }

  // ---- l: merge lane-halves (each lane summed its half's 32 k-rows/tile)
  {
    uint32_t a = __builtin_bit_cast(uint32_t, lsum), a2 = a;
    pl32swap(a, a2);
    float lf = __builtin_bit_cast(float, a) + __builtin_bit_cast(float, a2);
    if (lane < 32)
      lpar[((size_t)seg * B_ + b) * N_ + q0w + lane] = lf;
  }

  // ---- store O^T partials (bf16): col=q=l31, row d = dt*32+R*8+4*(lane>>5)+i
  const int hh = lane >> 5;
  bf16* op = Opar + (((size_t)seg * B_ + b) * N_ + q0w + l31) * C2_;
  #pragma unroll
  for (int dt = 0; dt < 4; ++dt) {
    #pragma unroll
    for (int R = 0; R < 4; ++R) {
      bf16x4 v;
      #pragma unroll
      for (int i = 0; i < 4; ++i) v[i] = (bf16)o_acc[dt][4 * R + i];
      *(bf16x4*)(op + dt * 32 + R * 8 + hh * 4) = v;
    }
  }
}

// ---------------------------------------------------------------------------
// Kernel 3: fused combine + final conv + residual.
// ---------------------------------------------------------------------------
template<int SEG>
__global__ __launch_bounds__(256) void final_kernel(
    const float* __restrict__ x, const float* __restrict__ wf,
    const float* __restrict__ bf_,
    const bf16* __restrict__ Opar, const float* __restrict__ lpar,
    float* __restrict__ out)
{
  __shared__ bf16 Ys[64][C2_ + 8];
  __shared__ float Linv[64];

  const int tid  = threadIdx.x;
  const int lane = tid & 63;
  const int w    = tid >> 6;
  const int n0   = blockIdx.x * 64;
  const int b    = blockIdx.y;
  const int l15  = lane & 15;
  const int lg   = lane >> 4;
  const int kbase = lg * 8;

  // ---- 1/l per row
  if (tid < 64) {
    float l = 0.f;
    #pragma unroll
    for (int s = 0; s < SEG; ++s)
      l += lpar[((size_t)s * B_ + b) * N_ + n0 + tid];
    Linv[tid] = 1.f / l;
  }
  __syncthreads();

  // ---- stage y tile (sum bf16 segs in f32, normalize, repack bf16)
  #pragma unroll
  for (int it = 0; it < 4; ++it) {
    int idx = it * 256 + tid;          // 0..1023 chunks of 8
    int r   = idx >> 4;
    int c8  = (idx & 15) * 8;
    float a[8] = {0.f, 0.f, 0.f, 0.f, 0.f, 0.f, 0.f, 0.f};
    #pragma unroll
    for (int s = 0; s < SEG; ++s) {
      bf16x8 v = *(const bf16x8*)(Opar
          + (((size_t)s * B_ + b) * N_ + n0 + r) * C2_ + c8);
      #pragma unroll
      for (int j = 0; j < 8; ++j) a[j] += (float)v[j];
    }
    float inv = Linv[r];
    bf16x8 y;
    #pragma unroll
    for (int j = 0; j < 8; ++j) y[j] = (bf16)(a[j] * inv);
    *(bf16x8*)&Ys[r][c8] = y;
  }
  __syncthreads();

  // ---- GEMM: wave w owns c-rows [64w, 64w+64)
  const f32x4 fzero = {0.f, 0.f, 0.f, 0.f};
  f32x4 acc[4][4];
  #pragma unroll
  for (int rt = 0; rt < 4; ++rt)
    #pragma unroll
    for (int ct = 0; ct < 4; ++ct) acc[rt][ct] = fzero;

  for (int kc = 0; kc < 4; ++kc) {
    bf16x8 bfr[4];
    #pragma unroll
    for (int ct = 0; ct < 4; ++ct)
      bfr[ct] = *(const bf16x8*)&Ys[ct * 16 + l15][kc * 32 + kbase];
    #pragma unroll
    for (int rt = 0; rt < 4; ++rt) {
      const float* wr = wf + (size_t)(w * 64 + rt * 16 + l15) * C2_ + kc * 32 + kbase;
      f32x4 lo = *(const f32x4*)wr;
      f32x4 hi = *(const f32x4*)(wr + 4);
      bf16x8 af;
      #pragma unroll
      for (int i = 0; i < 4; ++i) { af[i] = (bf16)lo[i]; af[4 + i] = (bf16)hi[i]; }
      #pragma unroll
      for (int ct = 0; ct < 4; ++ct)
        acc[rt][ct] = mfma16(af, bfr[ct], acc[rt][ct]);
    }
  }

  #pragma unroll
  for (int rt = 0; rt < 4; ++rt) {
    int cbase = w * 64 + rt * 16 + lg * 4;
    #pragma unroll
    for (int j = 0; j < 4; ++j) {
      float bias = bf_[cbase + j];
      #pragma unroll
      for (int ct = 0; ct < 4; ++ct) {
        int n = n0 + ct * 16 + l15;
        size_t idx = ((size_t)b * C_ + cbase + j) * N_ + n;
        out[idx] = x[idx] + bias + acc[rt][ct][j];
      }
    }
  }
}

// ---------------------------------------------------------------------------
extern "C" void kernel_launch(void* const* d_in, const int* in_sizes, int n_in,
                              void* d_out, int out_size, void* d_ws, size_t ws_size,
                              hipStream_t stream) {
  const float* x       = (const float*)d_in[0];
  const float* w_theta = (const float*)d_in[1];
  const float* b_theta = (const float*)d_in[2];
  const float* w_phi   = (const float*)d_in[3];
  const float* b_phi   = (const float*)d_in[4];
  const float* w_g     = (const float*)d_in[5];
  const float* b_g     = (const float*)d_in[6];
  const float* w_final = (const float*)d_in[7];
  const float* b_final = (const float*)d_in[8];
  float* out = (float*)d_out;

  char* ws = (char*)d_ws;
  const size_t SZB = (size_t)B_ * N_ * C2_ * sizeof(bf16);   // 4 MB each
  bf16*  th = (bf16*)(ws);
  bf16*  ph = (bf16*)(ws + SZB);
  bf16*  gt = (bf16*)(ws + 2 * SZB);
  bf16*  OparB = (bf16*)(ws + 3 * SZB);                      // SEG x 4 MB (bf16)

  proj_kernel<<<dim3(N_ / 64, B_), 256, 0, stream>>>(
      x, w_theta, b_theta, w_phi, b_phi, w_g, b_g, th, ph, gt);

  const size_t need8 = 3 * SZB + 8 * SZB + (size_t)8 * B_ * N_ * sizeof(float);
  if (ws_size >= need8) {
    // SEG=8: grid (32,4,8)=1024 blocks of 256 thr; 3 blocks/CU; TPS=8
    float* lpar = (float*)(ws + 3 * SZB + 8 * SZB);
    attn_kernel<8, N_ / 8 / 64><<<dim3(N_ / 128, B_, 8), 256, 0, stream>>>(
        th, ph, gt, OparB, lpar);
    final_kernel<8><<<dim3(N_ / 64, B_), 256, 0, stream>>>(
        x, w_final, b_final, OparB, lpar, out);
  } else {
    // fallback: SEG=4 (workspace-limited), same 64-row K tiles
    float* lpar = (float*)(ws + 3 * SZB + 4 * SZB);
    attn_kernel<4, N_ / 4 / 64><<<dim3(N_ / 128, B_, 4), 256, 0, stream>>>(
        th, ph, gt, OparB, lpar);
    final_kernel<4><<<dim3(N_ / 64, B_), 256, 0, stream>>>(
        x, w_final, b_final, OparB, lpar, out);
  }
}

// Round 5
// 79.930 us; speedup vs baseline: 1.2751x; 1.0969x over previous
//
#include <hip/hip_runtime.h>

#define B_ 4
#define C_ 256
#define C2_ 128
#define N_ 4096
#define SEG_ 4
#define TPS_ (N_ / 64 / SEG_)   // 16 KV tiles (64 rows each) per segment
#define LOG2E_ 1.4426950408889634f
#define SHIFT2_ 43.28085122666891f   // 30 * log2(e); softmax in exp2 domain

typedef __bf16 bf16;
typedef __bf16 bf16x8 __attribute__((ext_vector_type(8)));
typedef __bf16 bf16x4 __attribute__((ext_vector_type(4)));
typedef __bf16 bf16x2 __attribute__((ext_vector_type(2)));
typedef float f32x4 __attribute__((ext_vector_type(4)));
typedef float f32x16 __attribute__((ext_vector_type(16)));
typedef unsigned int u32x4 __attribute__((ext_vector_type(4)));

__device__ __forceinline__ f32x4 mfma16(bf16x8 a, bf16x8 b, f32x4 c) {
  return __builtin_amdgcn_mfma_f32_16x16x32_bf16(a, b, c, 0, 0, 0);
}
__device__ __forceinline__ f32x16 mfma32(bf16x8 a, bf16x8 b, f32x16 c) {
  return __builtin_amdgcn_mfma_f32_32x32x16_bf16(a, b, c, 0, 0, 0);
}

__device__ __forceinline__ float fexp2(float x) {
#if __has_builtin(__builtin_amdgcn_exp2f)
  return __builtin_amdgcn_exp2f(x);
#else
  return exp2f(x);
#endif
}

// async global->LDS, 16B per lane (dest = wave-uniform base + lane*16)
typedef const __attribute__((address_space(1))) uint32_t* gas_ptr;
typedef __attribute__((address_space(3))) uint32_t* las_ptr;
__device__ __forceinline__ void gld_lds16(const bf16* g, bf16* l) {
  __builtin_amdgcn_global_load_lds((gas_ptr)g, (las_ptr)l, 16, 0, 0);
}

// pack two f32 -> one dword of 2 bf16
__device__ __forceinline__ uint32_t pk2(float a, float b) {
  bf16x2 v; v[0] = (bf16)a; v[1] = (bf16)b;
  return __builtin_bit_cast(uint32_t, v);
}
// v_permlane32_swap_b32: a[l>=32] <-> b[l<32]  (VALU cross-lane, no LDS pipe)
__device__ __forceinline__ void pl32swap(uint32_t& a, uint32_t& b) {
  asm volatile("v_permlane32_swap_b32 %0, %1" : "+v"(a), "+v"(b));
}

// exp2-domain softmax numerator + VALU row-sum partial + bf16 pack/transpose
__device__ __forceinline__ void exp_pack(const f32x16& s, float& lsum,
                                         bf16x8& pf0, bf16x8& pf1) {
  float p[16];
  #pragma unroll
  for (int r = 0; r < 16; ++r) p[r] = fexp2(s[r] - SHIFT2_);
  float a0 = (p[0] + p[1]) + (p[2] + p[3]);
  float a1 = (p[4] + p[5]) + (p[6] + p[7]);
  float a2 = (p[8] + p[9]) + (p[10] + p[11]);
  float a3 = (p[12] + p[13]) + (p[14] + p[15]);
  lsum += (a0 + a1) + (a2 + a3);
  uint32_t A[4], Bb[4];
  #pragma unroll
  for (int G = 0; G < 4; ++G) {
    A[G]  = pk2(p[4 * G + 0], p[4 * G + 1]);
    Bb[G] = pk2(p[4 * G + 2], p[4 * G + 3]);
  }
  pl32swap(A[0], A[1]);  pl32swap(Bb[0], Bb[1]);
  { u32x4 dv = {A[0], Bb[0], A[1], Bb[1]}; pf0 = __builtin_bit_cast(bf16x8, dv); }
  pl32swap(A[2], A[3]);  pl32swap(Bb[2], Bb[3]);
  { u32x4 dv = {A[2], Bb[2], A[3], Bb[3]}; pf1 = __builtin_bit_cast(bf16x8, dv); }
}

// 32x32x16 fragment layouts:
//  A/B: lane = idx%32 + 32*((k%16)/8), elem = k%8 (8 bf16 / 4 VGPRs)
//  C/D: col = lane&31, row = (reg&3) + 8*(reg>>2) + 4*(lane>>5)
// Operand storage (fragment-major, wave reads = linear 1KB):
//  theta/phi: [b][n/32][ks 8][64][8]   (theta pre-scaled by log2e)
//  g (V^T):   [b][n/32 chunk][dtile 4][ks2 2][64][8] (8KB per 32-row chunk)

// ---------------------------------------------------------------------------
// Kernel 1: fused 3-way 1x1-conv projections, fragment-major outputs.
// ---------------------------------------------------------------------------
__global__ __launch_bounds__(256) void proj_kernel(
    const float* __restrict__ x,
    const float* __restrict__ w0, const float* __restrict__ b0,
    const float* __restrict__ w1, const float* __restrict__ b1,
    const float* __restrict__ w2, const float* __restrict__ b2,
    bf16* __restrict__ o0, bf16* __restrict__ o1, bf16* __restrict__ o2)
{
  __shared__ bf16 Xs[64][C_];   // [n][c], 16B block cb swizzled: cb ^= (n&7)
  const int tid  = threadIdx.x;
  const int lane = tid & 63;
  const int w    = tid >> 6;
  const int n0   = blockIdx.x * 64;
  const int b    = blockIdx.y;
  const int l15  = lane & 15;
  const int lg   = lane >> 4;
  const float* xb = x + (size_t)b * C_ * N_;

  // stage X^T: thread owns row n=lane, wave w covers c in [64w, 64w+64)
  {
    const int nl = lane;
    #pragma unroll
    for (int g = 0; g < 8; ++g) {
      int c0 = w * 64 + g * 8;
      bf16x8 h;
      #pragma unroll
      for (int i = 0; i < 8; ++i)
        h[i] = (bf16)xb[(size_t)(c0 + i) * N_ + n0 + nl];
      int cbs = (c0 >> 3) ^ (nl & 7);
      *(bf16x8*)&Xs[nl][cbs * 8] = h;
    }
  }
  __syncthreads();

  const f32x4 fzero = {0.f, 0.f, 0.f, 0.f};
  f32x4 acc[3][2][4];
  #pragma unroll
  for (int p = 0; p < 3; ++p)
    #pragma unroll
    for (int ot = 0; ot < 2; ++ot)
      #pragma unroll
      for (int nt = 0; nt < 4; ++nt) acc[p][ot][nt] = fzero;

  const float* Wp[3] = {w0, w1, w2};
  const int arow = w * 32 + l15;
  const int kbase = lg * 8;

  for (int kc = 0; kc < 8; ++kc) {
    bf16x8 bfr[4];
    #pragma unroll
    for (int nt = 0; nt < 4; ++nt) {
      int n = nt * 16 + l15;
      int cbs = (kc * 4 + lg) ^ (n & 7);
      bfr[nt] = *(const bf16x8*)&Xs[n][cbs * 8];
    }
    #pragma unroll
    for (int p = 0; p < 3; ++p) {
      #pragma unroll
      for (int ot = 0; ot < 2; ++ot) {
        const float* wr = Wp[p] + (size_t)(arow + ot * 16) * C_ + kc * 32 + kbase;
        f32x4 lo = *(const f32x4*)wr;
        f32x4 hi = *(const f32x4*)(wr + 4);
        bf16x8 af;
        if (p == 0) {
          #pragma unroll
          for (int i = 0; i < 4; ++i) {
            af[i]     = (bf16)(lo[i] * LOG2E_);
            af[4 + i] = (bf16)(hi[i] * LOG2E_);
          }
        } else {
          #pragma unroll
          for (int i = 0; i < 4; ++i) { af[i] = (bf16)lo[i]; af[4 + i] = (bf16)hi[i]; }
        }
        #pragma unroll
        for (int nt = 0; nt < 4; ++nt)
          acc[p][ot][nt] = mfma16(af, bfr[nt], acc[p][ot][nt]);
      }
    }
  }

  // ---- theta (p=0, log2e-scaled), phi (p=1): [b][n/32][ks 8][64][8]
  const float* Bp[3] = {b0, b1, b2};
  bf16* Op2[2] = {o0, o1};
  #pragma unroll
  for (int p = 0; p < 2; ++p) {
    bf16* dst = Op2[p] + (size_t)b * 128 * 8 * 512;
    #pragma unroll
    for (int ot = 0; ot < 2; ++ot) {
      int ks = w * 2 + ot;            // c>>4 (c = w*32+ot*16+lg*4+j)
      float bv[4];
      #pragma unroll
      for (int j = 0; j < 4; ++j) {
        float t = Bp[p][w * 32 + ot * 16 + lg * 4 + j];
        bv[j] = (p == 0) ? t * LOG2E_ : t;
      }
      #pragma unroll
      for (int nt = 0; nt < 4; ++nt) {
        int qtile = (n0 >> 5) + (nt >> 1);
        int lanep = ((nt & 1) * 16 + l15) + 32 * (lg >> 1);
        int elemb = (lg & 1) * 4;
        bf16x4 ov;
        #pragma unroll
        for (int j = 0; j < 4; ++j) ov[j] = (bf16)(acc[p][ot][nt][j] + bv[j]);
        *(bf16x4*)(dst + ((size_t)(qtile * 8 + ks) * 64 + lanep) * 8 + elemb) = ov;
      }
    }
  }
  // ---- g (p=2): [b][n/32 chunk][dtile 4][ks2 2][64][8]  (8KB per chunk)
  {
    bf16* dst = o2 + (size_t)b * 128 * 4096;
    const int t32b = n0 >> 5;
    #pragma unroll
    for (int ot = 0; ot < 2; ++ot) {
      #pragma unroll
      for (int j = 0; j < 4; ++j) {
        float bv = b2[w * 32 + ot * 16 + lg * 4 + j];
        int d31 = ot * 16 + lg * 4 + j;        // d&31 (dtile = w)
        #pragma unroll
        for (int nt = 0; nt < 4; ++nt) {
          int t32 = t32b + (nt >> 1);          // 32-row chunk index
          int ks2 = nt & 1;                    // 16-row k-slice within chunk
          int lanep = d31 + 32 * (l15 >> 3);
          dst[((size_t)((t32 * 4 + w) * 2 + ks2) * 64 + lanep) * 8 + (l15 & 7)] =
              (bf16)(acc[2][ot][nt][j] + bv);
        }
      }
    }
  }
}

// ---------------------------------------------------------------------------
// Kernel 2: flash attention. 256 thr (4 waves), wave = 32 q-rows, 64-row KV
// tiles, SEG=4 (round-0 proven geometry). K in 32KB dbuf LDS via
// global_load_lds; V fragments DIRECT from global/L2, full 16-frag tile
// prefetched BEFORE QK (~500cy MFMA/VALU cover for L2/L3 latency), issued
// BEFORE next-tile K-DMA so PV's vmcnt doesn't wait on the DMA.
// Dual-chain QK (s0,s1 interleaved: breaks MFMA dep-latency serialization,
// the round-4 regression). exp1 overlaps PV0. One barrier per tile.
// launch_bounds(256,2): ~215 regs peak < 256 cap -> no spill; 2 blocks/CU.
// ---------------------------------------------------------------------------
template<int SEG, int TPS>
__global__ __launch_bounds__(256, 2) void attn_kernel(
    const bf16* __restrict__ qf_, const bf16* __restrict__ kf_,
    const bf16* __restrict__ vf_,
    bf16* __restrict__ Opar, float* __restrict__ lpar)
{
  __shared__ bf16 Kb[2][8192];   // [chunk 2][ks 8][64][8] per 64-row K tile

  const int tid  = threadIdx.x;
  const int lane = tid & 63;
  const int w    = tid >> 6;       // 0..3
  const int l31  = lane & 31;
  const int b    = blockIdx.y;
  const int seg  = blockIdx.z;
  const int q0w  = blockIdx.x * 128 + w * 32;   // wave's 32 q-rows

  // Q fragments (B operand of S^T = K Q^T): 8 coalesced 1KB loads
  bf16x8 qf[8];
  {
    const bf16* qb = qf_ + ((size_t)(b * 128 + (q0w >> 5))) * 4096 + lane * 8;
    #pragma unroll
    for (int ks = 0; ks < 8; ++ks)
      qf[ks] = *(const bf16x8*)(qb + ks * 512);
  }

  const bf16* ks_p = kf_ + (size_t)b * 128 * 4096 + (size_t)(seg * TPS) * 8192 + tid * 8;
  const bf16* vs_b = vf_ + (size_t)b * 128 * 4096 + (size_t)(seg * TPS) * 8192 + lane * 8;

  // prologue: stage K tile 0 into buffer 0 (256 thr x 16B = 4KB per call)
  #pragma unroll
  for (int pp = 0; pp < 4; ++pp)
    gld_lds16(ks_p + pp * 2048, &Kb[0][pp * 2048 + tid * 8]);
  __syncthreads();

  f32x16 o_acc[4];
  #pragma unroll
  for (int dt = 0; dt < 4; ++dt)
    #pragma unroll
    for (int r = 0; r < 16; ++r) o_acc[dt][r] = 0.f;
  float lsum = 0.f;   // this lane-half's partial row sum (q = l31)

  for (int t = 0; t < TPS; ++t) {
    const int cur = t & 1;

    // ---- full V tile prefetch (16 x 1KB coalesced; consumed in PV0/PV1
    // after QK+exp). Issued FIRST so PV's vmcnt waits only on V, not K-DMA.
    const bf16* Vg = vs_b + (size_t)t * 8192;
    bf16x8 vfr[16];
    #pragma unroll
    for (int i = 0; i < 16; ++i)
      vfr[i] = *(const bf16x8*)(Vg + i * 512);

    // ---- issue next K tile's DMA (drained at this tile's barrier)
    if (t + 1 < TPS) {
      const bf16* ksn = ks_p + (size_t)(t + 1) * 8192;
      #pragma unroll
      for (int pp = 0; pp < 4; ++pp)
        gld_lds16(ksn + pp * 2048, &Kb[cur ^ 1][pp * 2048 + tid * 8]);
    }
    const bf16* Kc = Kb[cur];

    // ---- S^T = K Q^T, BOTH 32-row halves interleaved (2 indep MFMA chains)
    f32x16 s0, s1;
    #pragma unroll
    for (int r = 0; r < 16; ++r) { s0[r] = 0.f; s1[r] = 0.f; }
    __builtin_amdgcn_s_setprio(1);
    #pragma unroll
    for (int ks = 0; ks < 8; ++ks) {
      bf16x8 k0 = *(const bf16x8*)&Kc[(ks * 64 + lane) * 8];
      bf16x8 k1 = *(const bf16x8*)&Kc[4096 + (ks * 64 + lane) * 8];
      s0 = mfma32(k0, qf[ks], s0);
      s1 = mfma32(k1, qf[ks], s1);
    }
    __builtin_amdgcn_s_setprio(0);

    // ---- half 0: exp/pack then PV (V frag i = dt*2 + ks2)
    bf16x8 pf0, pf1;
    exp_pack(s0, lsum, pf0, pf1);
    __builtin_amdgcn_s_setprio(1);
    #pragma unroll
    for (int dt = 0; dt < 4; ++dt)
      o_acc[dt] = mfma32(vfr[dt * 2 + 0], pf0, o_acc[dt]);
    #pragma unroll
    for (int dt = 0; dt < 4; ++dt)
      o_acc[dt] = mfma32(vfr[dt * 2 + 1], pf1, o_acc[dt]);
    __builtin_amdgcn_s_setprio(0);

    // ---- half 1: exp/pack (VALU overlaps PV0's MFMAs) then PV
    bf16x8 pf2, pf3;
    exp_pack(s1, lsum, pf2, pf3);
    __builtin_amdgcn_s_setprio(1);
    #pragma unroll
    for (int dt = 0; dt < 4; ++dt)
      o_acc[dt] = mfma32(vfr[8 + dt * 2 + 0], pf2, o_acc[dt]);
    #pragma unroll
    for (int dt = 0; dt < 4; ++dt)
      o_acc[dt] = mfma32(vfr[8 + dt * 2 + 1], pf3, o_acc[dt]);
    __builtin_amdgcn_s_setprio(0);

    // one barrier per tile: drains next K-tile DMA, protects K buffers
    __syncthreads();
  }

  // ---- l: merge lane-halves (each lane summed its half's 32 k-rows/tile)
  {
    uint32_t a = __builtin_bit_cast(uint32_t, lsum), a2 = a;
    pl32swap(a, a2);
    float lf = __builtin_bit_cast(float, a) + __builtin_bit_cast(float, a2);
    if (lane < 32)
      lpar[((size_t)seg * B_ + b) * N_ + q0w + lane] = lf;
  }

  // ---- store O^T partials (bf16): col=q=l31, row d = dt*32+R*8+4*(lane>>5)+i
  const int hh = lane >> 5;
  bf16* op = Opar + (((size_t)seg * B_ + b) * N_ + q0w + l31) * C2_;
  #pragma unroll
  for (int dt = 0; dt < 4; ++dt) {
    #pragma unroll
    for (int R = 0; R < 4; ++R) {
      bf16x4 v;
      #pragma unroll
      for (int i = 0; i < 4; ++i) v[i] = (bf16)o_acc[dt][4 * R + i];
      *(bf16x4*)(op + dt * 32 + R * 8 + hh * 4) = v;
    }
  }
}

// ---------------------------------------------------------------------------
// Kernel 3: fused combine + final conv + residual.
// ---------------------------------------------------------------------------
template<int SEG>
__global__ __launch_bounds__(256) void final_kernel(
    const float* __restrict__ x, const float* __restrict__ wf,
    const float* __restrict__ bf_,
    const bf16* __restrict__ Opar, const float* __restrict__ lpar,
    float* __restrict__ out)
{
  __shared__ bf16 Ys[64][C2_ + 8];
  __shared__ float Linv[64];

  const int tid  = threadIdx.x;
  const int lane = tid & 63;
  const int w    = tid >> 6;
  const int n0   = blockIdx.x * 64;
  const int b    = blockIdx.y;
  const int l15  = lane & 15;
  const int lg   = lane >> 4;
  const int kbase = lg * 8;

  // ---- 1/l per row
  if (tid < 64) {
    float l = 0.f;
    #pragma unroll
    for (int s = 0; s < SEG; ++s)
      l += lpar[((size_t)s * B_ + b) * N_ + n0 + tid];
    Linv[tid] = 1.f / l;
  }
  __syncthreads();

  // ---- stage y tile (sum bf16 segs in f32, normalize, repack bf16)
  #pragma unroll
  for (int it = 0; it < 4; ++it) {
    int idx = it * 256 + tid;          // 0..1023 chunks of 8
    int r   = idx >> 4;
    int c8  = (idx & 15) * 8;
    float a[8] = {0.f, 0.f, 0.f, 0.f, 0.f, 0.f, 0.f, 0.f};
    #pragma unroll
    for (int s = 0; s < SEG; ++s) {
      bf16x8 v = *(const bf16x8*)(Opar
          + (((size_t)s * B_ + b) * N_ + n0 + r) * C2_ + c8);
      #pragma unroll
      for (int j = 0; j < 8; ++j) a[j] += (float)v[j];
    }
    float inv = Linv[r];
    bf16x8 y;
    #pragma unroll
    for (int j = 0; j < 8; ++j) y[j] = (bf16)(a[j] * inv);
    *(bf16x8*)&Ys[r][c8] = y;
  }
  __syncthreads();

  // ---- GEMM: wave w owns c-rows [64w, 64w+64)
  const f32x4 fzero = {0.f, 0.f, 0.f, 0.f};
  f32x4 acc[4][4];
  #pragma unroll
  for (int rt = 0; rt < 4; ++rt)
    #pragma unroll
    for (int ct = 0; ct < 4; ++ct) acc[rt][ct] = fzero;

  for (int kc = 0; kc < 4; ++kc) {
    bf16x8 bfr[4];
    #pragma unroll
    for (int ct = 0; ct < 4; ++ct)
      bfr[ct] = *(const bf16x8*)&Ys[ct * 16 + l15][kc * 32 + kbase];
    #pragma unroll
    for (int rt = 0; rt < 4; ++rt) {
      const float* wr = wf + (size_t)(w * 64 + rt * 16 + l15) * C2_ + kc * 32 + kbase;
      f32x4 lo = *(const f32x4*)wr;
      f32x4 hi = *(const f32x4*)(wr + 4);
      bf16x8 af;
      #pragma unroll
      for (int i = 0; i < 4; ++i) { af[i] = (bf16)lo[i]; af[4 + i] = (bf16)hi[i]; }
      #pragma unroll
      for (int ct = 0; ct < 4; ++ct)
        acc[rt][ct] = mfma16(af, bfr[ct], acc[rt][ct]);
    }
  }

  #pragma unroll
  for (int rt = 0; rt < 4; ++rt) {
    int cbase = w * 64 + rt * 16 + lg * 4;
    #pragma unroll
    for (int j = 0; j < 4; ++j) {
      float bias = bf_[cbase + j];
      #pragma unroll
      for (int ct = 0; ct < 4; ++ct) {
        int n = n0 + ct * 16 + l15;
        size_t idx = ((size_t)b * C_ + cbase + j) * N_ + n;
        out[idx] = x[idx] + bias + acc[rt][ct][j];
      }
    }
  }
}

// ---------------------------------------------------------------------------
extern "C" void kernel_launch(void* const* d_in, const int* in_sizes, int n_in,
                              void* d_out, int out_size, void* d_ws, size_t ws_size,
                              hipStream_t stream) {
  const float* x       = (const float*)d_in[0];
  const float* w_theta = (const float*)d_in[1];
  const float* b_theta = (const float*)d_in[2];
  const float* w_phi   = (const float*)d_in[3];
  const float* b_phi   = (const float*)d_in[4];
  const float* w_g     = (const float*)d_in[5];
  const float* b_g     = (const float*)d_in[6];
  const float* w_final = (const float*)d_in[7];
  const float* b_final = (const float*)d_in[8];
  float* out = (float*)d_out;

  char* ws = (char*)d_ws;
  const size_t SZB = (size_t)B_ * N_ * C2_ * sizeof(bf16);   // 4 MB each
  bf16*  th = (bf16*)(ws);
  bf16*  ph = (bf16*)(ws + SZB);
  bf16*  gt = (bf16*)(ws + 2 * SZB);
  bf16*  OparB = (bf16*)(ws + 3 * SZB);                      // SEG_ x 4 MB (bf16)
  float* lpar  = (float*)(ws + 3 * SZB + SEG_ * SZB);        // 256 KB

  proj_kernel<<<dim3(N_ / 64, B_), 256, 0, stream>>>(
      x, w_theta, b_theta, w_phi, b_phi, w_g, b_g, th, ph, gt);
  attn_kernel<SEG_, TPS_><<<dim3(N_ / 128, B_, SEG_), 256, 0, stream>>>(
      th, ph, gt, OparB, lpar);
  final_kernel<SEG_><<<dim3(N_ / 64, B_), 256, 0, stream>>>(
      x, w_final, b_final, OparB, lpar, out);
}